// Round 1
// baseline (1113.899 us; speedup 1.0000x reference)
//
#include <hip/hip_runtime.h>

// Problem constants (inputs: (32,64,32,32) fp32; embed: (64,1024) fp32)
#define N_PIX  32768   // B*H*W
#define C_DIM  64
#define K_EMB  1024
#define HW     1024    // H*W
#define SPLIT  8
#define KCHUNK (K_EMB / SPLIT)  // 128

// d_out layout (float32, concatenated in return order):
//   [0 .. 2097151]           quantized_out (B,C,H,W)
//   [2097152]                loss
//   [2097153 .. 2129920]     encoding_indices (as float)
//   [2129921]                perplexity
#define OUT_Q_OFF    0
#define OUT_LOSS_OFF 2097152
#define OUT_IDX_OFF  2097153
#define OUT_PERP_OFF 2129921

// ws layout:
//   @0      e2[1024] floats
//   @4096   counts[1024] uint
//   @8192   lossAcc float
//   @12288  packed best[32768] ull   (256 KB)

__device__ __forceinline__ unsigned long long pack_score(float d, int k) {
    unsigned int u = __float_as_uint(d);
    // monotone map: works for negative floats too (defensive)
    u = (u & 0x80000000u) ? ~u : (u | 0x80000000u);
    return ((unsigned long long)u << 32) | (unsigned int)k;
}

__global__ void k_e2(const float* __restrict__ embed, float* __restrict__ e2) {
    int k = blockIdx.x * blockDim.x + threadIdx.x;  // 0..1023
    float s = 0.f;
#pragma unroll
    for (int c = 0; c < C_DIM; ++c) {
        float v = embed[c * K_EMB + k];
        s = fmaf(v, v, s);
    }
    e2[k] = s;
}

__global__ __launch_bounds__(256, 4) void k_score(
    const float* __restrict__ inp, const float* __restrict__ embed,
    const float* __restrict__ e2, unsigned long long* __restrict__ best) {
    const int n  = blockIdx.x * 256 + threadIdx.x;   // pixel
    const int b  = n >> 10;
    const int hw = n & 1023;
    const float* xp = inp + b * (C_DIM * HW) + hw;

    float x[C_DIM];
#pragma unroll
    for (int c = 0; c < C_DIM; ++c) x[c] = xp[c * HW];

    float xx = 0.f;
#pragma unroll
    for (int c = 0; c < C_DIM; ++c) xx = fmaf(x[c], x[c], xx);

    const int kbase = blockIdx.y * KCHUNK;
    unsigned long long bestp = ~0ull;

    for (int k0 = kbase; k0 < kbase + KCHUNK; k0 += 4) {
        float a0 = 0.f, a1 = 0.f, a2 = 0.f, a3 = 0.f;
#pragma unroll
        for (int c = 0; c < C_DIM; ++c) {
            const float4 e = *reinterpret_cast<const float4*>(embed + c * K_EMB + k0);
            a0 = fmaf(x[c], e.x, a0);
            a1 = fmaf(x[c], e.y, a1);
            a2 = fmaf(x[c], e.z, a2);
            a3 = fmaf(x[c], e.w, a3);
        }
        const float4 ee = *reinterpret_cast<const float4*>(e2 + k0);
        const float base = xx;
        float d0 = fmaf(-2.f, a0, base + ee.x);
        float d1 = fmaf(-2.f, a1, base + ee.y);
        float d2 = fmaf(-2.f, a2, base + ee.z);
        float d3 = fmaf(-2.f, a3, base + ee.w);
        unsigned long long p;
        p = pack_score(d0, k0);     if (p < bestp) bestp = p;
        p = pack_score(d1, k0 + 1); if (p < bestp) bestp = p;
        p = pack_score(d2, k0 + 2); if (p < bestp) bestp = p;
        p = pack_score(d3, k0 + 3); if (p < bestp) bestp = p;
    }
    atomicMin(best + n, bestp);
}

__global__ __launch_bounds__(256) void k_final(
    const float* __restrict__ inp, const float* __restrict__ embed,
    const unsigned long long* __restrict__ best,
    unsigned int* __restrict__ counts, float* __restrict__ lossAcc,
    float* __restrict__ out_q, float* __restrict__ out_idx) {
    __shared__ unsigned int hcnt[K_EMB];
    const int tid = threadIdx.x;
    for (int i = tid; i < K_EMB; i += 256) hcnt[i] = 0;
    __syncthreads();

    const int n  = blockIdx.x * 256 + tid;
    const int b  = n >> 10;
    const int hw = n & 1023;
    const int k  = (int)(unsigned int)(best[n] & 0xFFFFFFFFull);

    out_idx[n] = (float)k;
    atomicAdd(&hcnt[k], 1u);

    const float* xp = inp + b * (C_DIM * HW) + hw;
    float* qp = out_q + b * (C_DIM * HW) + hw;
    float ls = 0.f;
#pragma unroll
    for (int c = 0; c < C_DIM; ++c) {
        float q  = embed[c * K_EMB + k];   // divergent gather, L2-resident table
        float xv = xp[c * HW];
        float d  = q - xv;
        ls = fmaf(d, d, ls);
        qp[c * HW] = q;
    }
    // wave64 reduce of loss partial
    for (int off = 32; off > 0; off >>= 1) ls += __shfl_down(ls, off, 64);
    if ((tid & 63) == 0) atomicAdd(lossAcc, ls);

    __syncthreads();
    for (int i = tid; i < K_EMB; i += 256) {
        unsigned int cc = hcnt[i];
        if (cc) atomicAdd(counts + i, cc);
    }
}

__global__ __launch_bounds__(1024) void k_scalar(
    const unsigned int* __restrict__ counts, const float* __restrict__ lossAcc,
    float* __restrict__ out_loss, float* __restrict__ out_perp) {
    __shared__ float red[16];
    const int tid = threadIdx.x;  // 0..1023
    float p = (float)counts[tid] * (1.0f / (float)N_PIX);
    float t = p * logf(p + 1e-10f);   // p==0 -> exactly 0, matches reference
    for (int off = 32; off > 0; off >>= 1) t += __shfl_down(t, off, 64);
    if ((tid & 63) == 0) red[tid >> 6] = t;
    __syncthreads();
    if (tid == 0) {
        float s = 0.f;
#pragma unroll
        for (int i = 0; i < 16; ++i) s += red[i];
        *out_perp = expf(-s);
        *out_loss = 0.25f * (*lossAcc) * (1.0f / (float)(N_PIX * C_DIM));
    }
}

extern "C" void kernel_launch(void* const* d_in, const int* in_sizes, int n_in,
                              void* d_out, int out_size, void* d_ws, size_t ws_size,
                              hipStream_t stream) {
    const float* inp   = (const float*)d_in[0];
    const float* embed = (const float*)d_in[1];
    float* out = (float*)d_out;

    char* ws = (char*)d_ws;
    float*              e2      = (float*)(ws + 0);
    unsigned int*       counts  = (unsigned int*)(ws + 4096);
    float*              lossAcc = (float*)(ws + 8192);
    unsigned long long* best    = (unsigned long long*)(ws + 12288);

    // zero counts + lossAcc; init packed-best to all-ones (max)
    hipMemsetAsync(ws + 4096, 0, 4096 + 16, stream);
    hipMemsetAsync(best, 0xFF, (size_t)N_PIX * 8, stream);

    k_e2<<<dim3(K_EMB / 256), dim3(256), 0, stream>>>(embed, e2);
    k_score<<<dim3(N_PIX / 256, SPLIT), dim3(256), 0, stream>>>(inp, embed, e2, best);
    k_final<<<dim3(N_PIX / 256), dim3(256), 0, stream>>>(
        inp, embed, best, counts, lossAcc, out + OUT_Q_OFF, out + OUT_IDX_OFF);
    k_scalar<<<dim3(1), dim3(1024), 0, stream>>>(counts, lossAcc,
        out + OUT_LOSS_OFF, out + OUT_PERP_OFF);
}

// Round 2
// 374.721 us; speedup vs baseline: 2.9726x; 2.9726x over previous
//
#include <hip/hip_runtime.h>

// Problem constants (inputs: (32,64,32,32) fp32; embed: (64,1024) fp32)
#define N_PIX  32768   // B*H*W
#define C_DIM  64
#define K_EMB  1024
#define HW     1024    // H*W
#define SPLIT  8
#define KCHUNK (K_EMB / SPLIT)  // 128

// d_out layout (float32, concatenated in return order):
//   quantized_out (B,C,H,W) | loss | encoding_indices | perplexity
#define OUT_Q_OFF    0
#define OUT_LOSS_OFF 2097152
#define OUT_IDX_OFF  2097153
#define OUT_PERP_OFF 2129921

// ws layout:
//   @0      e2[1024] floats
//   @4096   counts[1024] uint
//   @8192   lossAcc float
//   @12288  packed best[32768] ull   (256 KB)

__device__ __forceinline__ unsigned long long pack_score(float d, int k) {
    unsigned int u = __float_as_uint(d);
    u = (u & 0x80000000u) ? ~u : (u | 0x80000000u);  // monotone map, safe for negatives
    return ((unsigned long long)u << 32) | (unsigned int)k;
}

__global__ void k_e2(const float* __restrict__ embed, float* __restrict__ e2) {
    int k = blockIdx.x * blockDim.x + threadIdx.x;  // 0..1023
    float s = 0.f;
#pragma unroll
    for (int c = 0; c < C_DIM; ++c) {
        float v = embed[c * K_EMB + k];
        s = fmaf(v, v, s);
    }
    e2[k] = s;
}

// One thread per pixel; blockIdx.y selects a 128-wide K chunk.
// x[64] MUST stay in VGPRs: launch_bounds(256,2) allows 256 VGPRs, and the
// c-loop is chunked (16 float4 loads in flight max) to bound pressure.
__global__ __launch_bounds__(256, 2) void k_score(
    const float* __restrict__ inp, const float* __restrict__ embed,
    const float* __restrict__ e2, unsigned long long* __restrict__ best) {
    const int n  = blockIdx.x * 256 + threadIdx.x;   // pixel
    const int b  = n >> 10;
    const int hw = n & 1023;
    const float* xp = inp + b * (C_DIM * HW) + hw;

    float x[C_DIM];
#pragma unroll
    for (int c = 0; c < C_DIM; ++c) x[c] = xp[c * HW];

    float xx = 0.f;
#pragma unroll
    for (int c = 0; c < C_DIM; ++c) xx = fmaf(x[c], x[c], xx);

    const int kbase = blockIdx.y * KCHUNK;
    unsigned long long bestp = ~0ull;

    for (int k0 = kbase; k0 < kbase + KCHUNK; k0 += 4) {
        float a0 = 0.f, a1 = 0.f, a2 = 0.f, a3 = 0.f;
        // chunked: 4 outer iterations (not unrolled), 16 float4 loads each
        for (int cc = 0; cc < C_DIM; cc += 16) {
#pragma unroll
            for (int ci = 0; ci < 16; ++ci) {
                const int c = cc + ci;
                const float4 e = *reinterpret_cast<const float4*>(embed + c * K_EMB + k0);
                a0 = fmaf(x[c], e.x, a0);
                a1 = fmaf(x[c], e.y, a1);
                a2 = fmaf(x[c], e.z, a2);
                a3 = fmaf(x[c], e.w, a3);
            }
        }
        const float4 ee = *reinterpret_cast<const float4*>(e2 + k0);
        float d0 = fmaf(-2.f, a0, xx + ee.x);
        float d1 = fmaf(-2.f, a1, xx + ee.y);
        float d2 = fmaf(-2.f, a2, xx + ee.z);
        float d3 = fmaf(-2.f, a3, xx + ee.w);
        unsigned long long p;
        p = pack_score(d0, k0);     if (p < bestp) bestp = p;
        p = pack_score(d1, k0 + 1); if (p < bestp) bestp = p;
        p = pack_score(d2, k0 + 2); if (p < bestp) bestp = p;
        p = pack_score(d3, k0 + 3); if (p < bestp) bestp = p;
    }
    atomicMin(best + n, bestp);
}

__global__ __launch_bounds__(256) void k_final(
    const float* __restrict__ inp, const float* __restrict__ embed,
    const unsigned long long* __restrict__ best,
    unsigned int* __restrict__ counts, float* __restrict__ lossAcc,
    float* __restrict__ out_q, float* __restrict__ out_idx) {
    __shared__ unsigned int hcnt[K_EMB];
    const int tid = threadIdx.x;
    for (int i = tid; i < K_EMB; i += 256) hcnt[i] = 0;
    __syncthreads();

    const int n  = blockIdx.x * 256 + tid;
    const int b  = n >> 10;
    const int hw = n & 1023;
    const int k  = (int)(unsigned int)(best[n] & 0xFFFFFFFFull);

    out_idx[n] = (float)k;
    atomicAdd(&hcnt[k], 1u);

    const float* xp = inp + b * (C_DIM * HW) + hw;
    float* qp = out_q + b * (C_DIM * HW) + hw;
    float ls = 0.f;
#pragma unroll
    for (int c = 0; c < C_DIM; ++c) {
        float q  = embed[c * K_EMB + k];   // divergent gather, L2-resident table
        float xv = xp[c * HW];
        float d  = q - xv;
        ls = fmaf(d, d, ls);
        qp[c * HW] = q;
    }
    for (int off = 32; off > 0; off >>= 1) ls += __shfl_down(ls, off, 64);
    if ((tid & 63) == 0) atomicAdd(lossAcc, ls);

    __syncthreads();
    for (int i = tid; i < K_EMB; i += 256) {
        unsigned int cc = hcnt[i];
        if (cc) atomicAdd(counts + i, cc);
    }
}

__global__ __launch_bounds__(1024) void k_scalar(
    const unsigned int* __restrict__ counts, const float* __restrict__ lossAcc,
    float* __restrict__ out_loss, float* __restrict__ out_perp) {
    __shared__ float red[16];
    const int tid = threadIdx.x;  // 0..1023
    float p = (float)counts[tid] * (1.0f / (float)N_PIX);
    float t = p * logf(p + 1e-10f);   // p==0 -> exactly 0, matches reference
    for (int off = 32; off > 0; off >>= 1) t += __shfl_down(t, off, 64);
    if ((tid & 63) == 0) red[tid >> 6] = t;
    __syncthreads();
    if (tid == 0) {
        float s = 0.f;
#pragma unroll
        for (int i = 0; i < 16; ++i) s += red[i];
        *out_perp = expf(-s);
        *out_loss = 0.25f * (*lossAcc) * (1.0f / (float)(N_PIX * C_DIM));
    }
}

extern "C" void kernel_launch(void* const* d_in, const int* in_sizes, int n_in,
                              void* d_out, int out_size, void* d_ws, size_t ws_size,
                              hipStream_t stream) {
    const float* inp   = (const float*)d_in[0];
    const float* embed = (const float*)d_in[1];
    float* out = (float*)d_out;

    char* ws = (char*)d_ws;
    float*              e2      = (float*)(ws + 0);
    unsigned int*       counts  = (unsigned int*)(ws + 4096);
    float*              lossAcc = (float*)(ws + 8192);
    unsigned long long* best    = (unsigned long long*)(ws + 12288);

    hipMemsetAsync(ws + 4096, 0, 4096 + 16, stream);
    hipMemsetAsync(best, 0xFF, (size_t)N_PIX * 8, stream);

    k_e2<<<dim3(K_EMB / 256), dim3(256), 0, stream>>>(embed, e2);
    k_score<<<dim3(N_PIX / 256, SPLIT), dim3(256), 0, stream>>>(inp, embed, e2, best);
    k_final<<<dim3(N_PIX / 256), dim3(256), 0, stream>>>(
        inp, embed, best, counts, lossAcc, out + OUT_Q_OFF, out + OUT_IDX_OFF);
    k_scalar<<<dim3(1), dim3(1024), 0, stream>>>(counts, lossAcc,
        out + OUT_LOSS_OFF, out + OUT_PERP_OFF);
}

// Round 3
// 216.591 us; speedup vs baseline: 5.1429x; 1.7301x over previous
//
#include <hip/hip_runtime.h>

// Problem constants (inputs: (32,64,32,32) fp32; embed: (64,1024) fp32)
#define N_PIX  32768   // B*H*W
#define C_DIM  64
#define K_EMB  1024
#define HW     1024    // H*W
#define P_TILE 16      // pixels per block

// d_out layout (float32, concatenated in return order):
//   quantized_out (B,C,H,W) | loss | encoding_indices | perplexity
#define OUT_Q_OFF    0
#define OUT_LOSS_OFF 2097152
#define OUT_IDX_OFF  2097153
#define OUT_PERP_OFF 2129921

// ws layout: e2[1024] @0 | counts[1024] @4096 | lossAcc @8192

__device__ __forceinline__ unsigned long long pack_score(float d, int k) {
    unsigned int u = __float_as_uint(d);
    u = (u & 0x80000000u) ? ~u : (u | 0x80000000u);  // monotone map, negative-safe
    return ((unsigned long long)u << 32) | (unsigned int)k;
}

__global__ void k_e2(const float* __restrict__ embed, float* __restrict__ e2) {
    int k = blockIdx.x * blockDim.x + threadIdx.x;  // 0..1023
    float s = 0.f;
#pragma unroll
    for (int c = 0; c < C_DIM; ++c) {
        float v = embed[c * K_EMB + k];
        s = fmaf(v, v, s);
    }
    e2[k] = s;
}

// k-major cooperative kernel: 256 threads x 4 k's = all 1024 codes per block;
// 16 pixels staged in LDS. argmin(||x||^2 + ee - 2 x.e) == argmin(ee - 2 x.e),
// so ||x||^2 is dropped. Block covers full K -> argmin is block-final; fused
// epilogue does quantize/loss/histogram (x still in LDS).
__global__ __launch_bounds__(256, 2) void k_main(
    const float* __restrict__ inp, const float* __restrict__ embed,
    const float* __restrict__ e2, unsigned int* __restrict__ counts,
    float* __restrict__ lossAcc, float* __restrict__ out_q,
    float* __restrict__ out_idx) {
    __shared__ float x_lds[C_DIM][P_TILE];            // 4 KB
    __shared__ unsigned long long red[4][P_TILE];     // 512 B
    __shared__ int ksel[P_TILE];

    const int tid = threadIdx.x;
    const int n0  = blockIdx.x * P_TILE;
    const int b   = n0 >> 10;
    const int hw0 = n0 & 1023;
    const float* xbase = inp + b * (C_DIM * HW);

    // stage x tile: tid -> (c = tid>>2, 4 pixels)
    {
        const int c  = tid >> 2;
        const int p4 = (tid & 3) * 4;
        const float4 v = *reinterpret_cast<const float4*>(xbase + c * HW + hw0 + p4);
        x_lds[c][p4 + 0] = v.x; x_lds[c][p4 + 1] = v.y;
        x_lds[c][p4 + 2] = v.z; x_lds[c][p4 + 3] = v.w;
    }
    __syncthreads();

    const int k0 = tid * 4;  // this thread's 4 codes (coalesced float4 across wave)
    float4 acc[P_TILE];
#pragma unroll
    for (int p = 0; p < P_TILE; ++p) acc[p] = make_float4(0.f, 0.f, 0.f, 0.f);

#pragma unroll 4
    for (int c = 0; c < C_DIM; ++c) {
        const float4 e4 = *reinterpret_cast<const float4*>(embed + c * K_EMB + k0);
#pragma unroll
        for (int p4 = 0; p4 < P_TILE; p4 += 4) {
            const float4 xv = *reinterpret_cast<const float4*>(&x_lds[c][p4]);  // broadcast
            acc[p4 + 0].x = fmaf(xv.x, e4.x, acc[p4 + 0].x);
            acc[p4 + 0].y = fmaf(xv.x, e4.y, acc[p4 + 0].y);
            acc[p4 + 0].z = fmaf(xv.x, e4.z, acc[p4 + 0].z);
            acc[p4 + 0].w = fmaf(xv.x, e4.w, acc[p4 + 0].w);
            acc[p4 + 1].x = fmaf(xv.y, e4.x, acc[p4 + 1].x);
            acc[p4 + 1].y = fmaf(xv.y, e4.y, acc[p4 + 1].y);
            acc[p4 + 1].z = fmaf(xv.y, e4.z, acc[p4 + 1].z);
            acc[p4 + 1].w = fmaf(xv.y, e4.w, acc[p4 + 1].w);
            acc[p4 + 2].x = fmaf(xv.z, e4.x, acc[p4 + 2].x);
            acc[p4 + 2].y = fmaf(xv.z, e4.y, acc[p4 + 2].y);
            acc[p4 + 2].z = fmaf(xv.z, e4.z, acc[p4 + 2].z);
            acc[p4 + 2].w = fmaf(xv.z, e4.w, acc[p4 + 2].w);
            acc[p4 + 3].x = fmaf(xv.w, e4.x, acc[p4 + 3].x);
            acc[p4 + 3].y = fmaf(xv.w, e4.y, acc[p4 + 3].y);
            acc[p4 + 3].z = fmaf(xv.w, e4.z, acc[p4 + 3].z);
            acc[p4 + 3].w = fmaf(xv.w, e4.w, acc[p4 + 3].w);
        }
    }

    // scores s = ee - 2*dot; per-pixel packed-min across the block
    const float4 ee = *reinterpret_cast<const float4*>(e2 + k0);
    const int wv = tid >> 6, ln = tid & 63;
#pragma unroll
    for (int p = 0; p < P_TILE; ++p) {
        const float s0 = fmaf(-2.f, acc[p].x, ee.x);
        const float s1 = fmaf(-2.f, acc[p].y, ee.y);
        const float s2 = fmaf(-2.f, acc[p].z, ee.z);
        const float s3 = fmaf(-2.f, acc[p].w, ee.w);
        unsigned long long m = pack_score(s0, k0), t;
        t = pack_score(s1, k0 + 1); if (t < m) m = t;
        t = pack_score(s2, k0 + 2); if (t < m) m = t;
        t = pack_score(s3, k0 + 3); if (t < m) m = t;
        for (int off = 32; off > 0; off >>= 1) {
            unsigned long long o = __shfl_down(m, off, 64);
            if (o < m) m = o;
        }
        if (ln == 0) red[wv][p] = m;
    }
    __syncthreads();
    if (tid < P_TILE) {
        unsigned long long m = red[0][tid];
        if (red[1][tid] < m) m = red[1][tid];
        if (red[2][tid] < m) m = red[2][tid];
        if (red[3][tid] < m) m = red[3][tid];
        const int k = (int)(unsigned int)(m & 0xFFFFFFFFull);
        ksel[tid] = k;
        out_idx[n0 + tid] = (float)k;
        atomicAdd(counts + k, 1u);
    }
    __syncthreads();

    // fused quantize + loss: tid -> (c, 4 pixels)
    {
        const int c  = tid >> 2;
        const int pb = (tid & 3) * 4;
        float ls = 0.f;
        float4 qv;
        float* qvp = &qv.x;
#pragma unroll
        for (int j = 0; j < 4; ++j) {
            const int k = ksel[pb + j];
            const float q  = embed[c * K_EMB + k];   // gather, L2-resident table
            const float xv = x_lds[c][pb + j];
            const float d  = q - xv;
            ls = fmaf(d, d, ls);
            qvp[j] = q;
        }
        *reinterpret_cast<float4*>(out_q + b * (C_DIM * HW) + c * HW + hw0 + pb) = qv;
        for (int off = 32; off > 0; off >>= 1) ls += __shfl_down(ls, off, 64);
        if (ln == 0) atomicAdd(lossAcc, ls);
    }
}

__global__ __launch_bounds__(1024) void k_scalar(
    const unsigned int* __restrict__ counts, const float* __restrict__ lossAcc,
    float* __restrict__ out_loss, float* __restrict__ out_perp) {
    __shared__ float red[16];
    const int tid = threadIdx.x;  // 0..1023
    float p = (float)counts[tid] * (1.0f / (float)N_PIX);
    float t = p * logf(p + 1e-10f);   // p==0 -> exactly 0, matches reference
    for (int off = 32; off > 0; off >>= 1) t += __shfl_down(t, off, 64);
    if ((tid & 63) == 0) red[tid >> 6] = t;
    __syncthreads();
    if (tid == 0) {
        float s = 0.f;
#pragma unroll
        for (int i = 0; i < 16; ++i) s += red[i];
        *out_perp = expf(-s);
        *out_loss = 0.25f * (*lossAcc) * (1.0f / (float)(N_PIX * C_DIM));
    }
}

extern "C" void kernel_launch(void* const* d_in, const int* in_sizes, int n_in,
                              void* d_out, int out_size, void* d_ws, size_t ws_size,
                              hipStream_t stream) {
    const float* inp   = (const float*)d_in[0];
    const float* embed = (const float*)d_in[1];
    float* out = (float*)d_out;

    char* ws = (char*)d_ws;
    float*        e2      = (float*)(ws + 0);
    unsigned int* counts  = (unsigned int*)(ws + 4096);
    float*        lossAcc = (float*)(ws + 8192);

    hipMemsetAsync(ws + 4096, 0, 4096 + 16, stream);  // counts + lossAcc

    k_e2<<<dim3(K_EMB / 256), dim3(256), 0, stream>>>(embed, e2);
    k_main<<<dim3(N_PIX / P_TILE), dim3(256), 0, stream>>>(
        inp, embed, e2, counts, lossAcc, out + OUT_Q_OFF, out + OUT_IDX_OFF);
    k_scalar<<<dim3(1), dim3(1024), 0, stream>>>(counts, lossAcc,
        out + OUT_LOSS_OFF, out + OUT_PERP_OFF);
}

// Round 4
// 194.179 us; speedup vs baseline: 5.7365x; 1.1154x over previous
//
#include <hip/hip_runtime.h>

// Problem constants (inputs: (32,64,32,32) fp32; embed: (64,1024) fp32)
#define N_PIX  32768   // B*H*W
#define C_DIM  64
#define K_EMB  1024
#define HW     1024    // H*W
#define P_TILE 16      // pixels per block

// d_out layout (float32, concatenated in return order):
//   quantized_out (B,C,H,W) | loss | encoding_indices | perplexity
#define OUT_Q_OFF    0
#define OUT_LOSS_OFF 2097152
#define OUT_IDX_OFF  2097153
#define OUT_PERP_OFF 2129921

// ws layout: counts[1024] @0 | lossAcc @4096

__device__ __forceinline__ unsigned long long pack_score(float d, int k) {
    unsigned int u = __float_as_uint(d);
    u = (u & 0x80000000u) ? ~u : (u | 0x80000000u);  // monotone map, negative-safe
    return ((unsigned long long)u << 32) | (unsigned int)k;
}

// k-major cooperative kernel: 256 threads x 4 k's = all 1024 codes per block;
// 16 pixels per block. x rows are block-uniform -> scalar (SGPR) loads, no LDS
// in the hot loop. ||e||^2 fused into the same loop (ee += e4*e4). Accumulators
// are 16 NAMED float4s in straight-line code so the compiler cannot demote them.
// argmin(||x||^2+||e||^2-2x.e) == argmin(||e||^2-2x.e): ||x||^2 dropped.
__global__ __launch_bounds__(256, 4) void k_main(
    const float* __restrict__ inp, const float* __restrict__ embed,
    unsigned int* __restrict__ counts, float* __restrict__ lossAcc,
    float* __restrict__ out_q, float* __restrict__ out_idx) {
    __shared__ unsigned long long red[4][P_TILE];
    __shared__ int ksel[P_TILE];

    const int tid = threadIdx.x;
    const int n0  = blockIdx.x * P_TILE;
    const int b   = n0 >> 10;
    const int hw0 = n0 & 1023;
    const float* __restrict__ xu = inp + b * (C_DIM * HW) + hw0;  // uniform

    const int k0 = tid * 4;  // this thread's 4 codes (coalesced float4 across wave)

    float4 a0 = {0,0,0,0}, a1 = {0,0,0,0}, a2 = {0,0,0,0}, a3 = {0,0,0,0};
    float4 a4 = {0,0,0,0}, a5 = {0,0,0,0}, a6 = {0,0,0,0}, a7 = {0,0,0,0};
    float4 a8 = {0,0,0,0}, a9 = {0,0,0,0}, a10 = {0,0,0,0}, a11 = {0,0,0,0};
    float4 a12 = {0,0,0,0}, a13 = {0,0,0,0}, a14 = {0,0,0,0}, a15 = {0,0,0,0};
    float4 ee = {0,0,0,0};

#define FMA_P(i, xv) \
    a##i.x = fmaf((xv), e4.x, a##i.x); \
    a##i.y = fmaf((xv), e4.y, a##i.y); \
    a##i.z = fmaf((xv), e4.z, a##i.z); \
    a##i.w = fmaf((xv), e4.w, a##i.w);

#pragma unroll 2
    for (int c = 0; c < C_DIM; ++c) {
        const float4 e4 = *reinterpret_cast<const float4*>(embed + c * K_EMB + k0);
        const float4* __restrict__ xr =
            reinterpret_cast<const float4*>(xu + c * HW);  // uniform -> s_load
        const float4 xq0 = xr[0], xq1 = xr[1], xq2 = xr[2], xq3 = xr[3];
        ee.x = fmaf(e4.x, e4.x, ee.x);
        ee.y = fmaf(e4.y, e4.y, ee.y);
        ee.z = fmaf(e4.z, e4.z, ee.z);
        ee.w = fmaf(e4.w, e4.w, ee.w);
        FMA_P(0,  xq0.x) FMA_P(1,  xq0.y) FMA_P(2,  xq0.z) FMA_P(3,  xq0.w)
        FMA_P(4,  xq1.x) FMA_P(5,  xq1.y) FMA_P(6,  xq1.z) FMA_P(7,  xq1.w)
        FMA_P(8,  xq2.x) FMA_P(9,  xq2.y) FMA_P(10, xq2.z) FMA_P(11, xq2.w)
        FMA_P(12, xq3.x) FMA_P(13, xq3.y) FMA_P(14, xq3.z) FMA_P(15, xq3.w)
    }
#undef FMA_P

    // per-pixel packed argmin across the block
    const int wv = tid >> 6, ln = tid & 63;
    const float4* accp[P_TILE] = {&a0,&a1,&a2,&a3,&a4,&a5,&a6,&a7,
                                  &a8,&a9,&a10,&a11,&a12,&a13,&a14,&a15};
#pragma unroll
    for (int p = 0; p < P_TILE; ++p) {
        const float4 ac = *accp[p];
        const float s0 = fmaf(-2.f, ac.x, ee.x);
        const float s1 = fmaf(-2.f, ac.y, ee.y);
        const float s2 = fmaf(-2.f, ac.z, ee.z);
        const float s3 = fmaf(-2.f, ac.w, ee.w);
        unsigned long long m = pack_score(s0, k0), t;
        t = pack_score(s1, k0 + 1); if (t < m) m = t;
        t = pack_score(s2, k0 + 2); if (t < m) m = t;
        t = pack_score(s3, k0 + 3); if (t < m) m = t;
        for (int off = 32; off > 0; off >>= 1) {
            unsigned long long o = __shfl_down(m, off, 64);
            if (o < m) m = o;
        }
        if (ln == 0) red[wv][p] = m;
    }
    __syncthreads();
    if (tid < P_TILE) {
        unsigned long long m = red[0][tid];
        if (red[1][tid] < m) m = red[1][tid];
        if (red[2][tid] < m) m = red[2][tid];
        if (red[3][tid] < m) m = red[3][tid];
        const int k = (int)(unsigned int)(m & 0xFFFFFFFFull);
        ksel[tid] = k;
        out_idx[n0 + tid] = (float)k;
        atomicAdd(counts + k, 1u);
    }
    __syncthreads();

    // fused quantize + loss: tid -> (c = tid>>2, 4 pixels); x re-read (L1/L2 hot)
    {
        const int c  = tid >> 2;
        const int pb = (tid & 3) * 4;
        float ls = 0.f;
        float4 qv;
        float* qvp = &qv.x;
        const float4 xv4 = *reinterpret_cast<const float4*>(xu + c * HW + pb);
        const float* xvp = &xv4.x;
#pragma unroll
        for (int j = 0; j < 4; ++j) {
            const int k = ksel[pb + j];
            const float q = embed[c * K_EMB + k];  // gather, L2-resident table
            const float d = q - xvp[j];
            ls = fmaf(d, d, ls);
            qvp[j] = q;
        }
        *reinterpret_cast<float4*>(out_q + b * (C_DIM * HW) + c * HW + hw0 + pb) = qv;
        for (int off = 32; off > 0; off >>= 1) ls += __shfl_down(ls, off, 64);
        if (ln == 0) atomicAdd(lossAcc, ls);
    }
}

__global__ __launch_bounds__(1024) void k_scalar(
    const unsigned int* __restrict__ counts, const float* __restrict__ lossAcc,
    float* __restrict__ out_loss, float* __restrict__ out_perp) {
    __shared__ float red[16];
    const int tid = threadIdx.x;  // 0..1023
    float p = (float)counts[tid] * (1.0f / (float)N_PIX);
    float t = p * logf(p + 1e-10f);   // p==0 -> exactly 0, matches reference
    for (int off = 32; off > 0; off >>= 1) t += __shfl_down(t, off, 64);
    if ((tid & 63) == 0) red[tid >> 6] = t;
    __syncthreads();
    if (tid == 0) {
        float s = 0.f;
#pragma unroll
        for (int i = 0; i < 16; ++i) s += red[i];
        *out_perp = expf(-s);
        *out_loss = 0.25f * (*lossAcc) * (1.0f / (float)(N_PIX * C_DIM));
    }
}

extern "C" void kernel_launch(void* const* d_in, const int* in_sizes, int n_in,
                              void* d_out, int out_size, void* d_ws, size_t ws_size,
                              hipStream_t stream) {
    const float* inp   = (const float*)d_in[0];
    const float* embed = (const float*)d_in[1];
    float* out = (float*)d_out;

    char* ws = (char*)d_ws;
    unsigned int* counts  = (unsigned int*)(ws + 0);
    float*        lossAcc = (float*)(ws + 4096);

    hipMemsetAsync(ws, 0, 4096 + 16, stream);  // counts + lossAcc

    k_main<<<dim3(N_PIX / P_TILE), dim3(256), 0, stream>>>(
        inp, embed, counts, lossAcc, out + OUT_Q_OFF, out + OUT_IDX_OFF);
    k_scalar<<<dim3(1), dim3(1024), 0, stream>>>(counts, lossAcc,
        out + OUT_LOSS_OFF, out + OUT_PERP_OFF);
}